// Round 5
// baseline (1837.563 us; speedup 1.0000x reference)
//
#include <hip/hip_runtime.h>
#include <hip/hip_bf16.h>

#define SEQ  2048
#define BAT  64
#define HID  128
#define LDSP 136   // padded LDS row: 272 B

// workspace layout (needs ~36 MiB, proven available earlier; 1 MiB guard before XB)
#define XB_OFF  (1u << 20)            // bf16 x, 32 MiB
#define IL_OFF  (35u << 20)           // f32 ilogm1[t][b], 512 KiB

typedef __bf16 bf16x8 __attribute__((ext_vector_type(8)));
typedef float  f32x4  __attribute__((ext_vector_type(4)));

#define MFMA(a,b,c) __builtin_amdgcn_mfma_f32_16x16x32_bf16((a),(b),(c),0,0,0)

__device__ __forceinline__ float sig_f(float x) {
    return __fdividef(1.0f, 1.0f + __expf(-x));
}
__device__ __forceinline__ float tanh_f(float x) {
    return 1.0f - __fdividef(2.0f, 1.0f + __expf(2.0f * x));
}
__device__ __forceinline__ bf16x8 cvt8(const float* p) {
    bf16x8 r;
    #pragma unroll
    for (int i = 0; i < 8; ++i) r[i] = (__bf16)p[i];
    return r;
}

// ---- pre-kernel 1: x f32 -> bf16, same [S][B][I] layout ----
__global__ void cvt_x_kernel(const float* __restrict__ x, __bf16* __restrict__ xb) {
    const int i = (blockIdx.x * 256 + threadIdx.x) * 4;
    const float4 v = *reinterpret_cast<const float4*>(x + i);
    __bf16 o[4];
    o[0] = (__bf16)v.x; o[1] = (__bf16)v.y; o[2] = (__bf16)v.z; o[3] = (__bf16)v.w;
    *reinterpret_cast<uint2*>(xb + i) = *reinterpret_cast<const uint2*>(o);
}

// ---- pre-kernel 2: ilogm1[t][b] = 1/ln(e + dts[b][t]) - 1 ----
__global__ void prep_ilog_kernel(const float* __restrict__ dts, float* __restrict__ il) {
    const int idx = blockIdx.x * 256 + threadIdx.x;
    const int b = idx >> 11, t = idx & 2047;
    const float l = __logf(2.718281828459045f + dts[idx]);
    il[t * BAT + b] = __fdividef(1.0f, l) - 1.0f;
}

// 32 WGs: blockIdx = dir*16 + batch_tile; each WG owns 4 chains; 8 waves, wave w
// owns gate dims j in [16w, 16w+16).
//
// x-BURST (R4): per 4-step chunk, one dense 16-MFMA block computes x@Wih + bias
// for all 4 steps; C reg r of lane q = (chain q, step dt=r).
//
// ROW-ROTATED hc tile (R4): at step dt, h(chain c) at row 4c+dt, c(chain c) at
// row 4c+((dt+2)&3); each step writes NEXT step's rows. Gate MFMA real output at
// reg dt -> C-in is the burst accumulator verbatim.
//
// R5 (this round): SSA / D!=C MFMA chains. MFMA's D and C are separate operands;
// writing `t = MFMA(A, B, xacc[g])` preserves xacc[g] with ZERO copy movs (the
// old `ai = xacc[g]; ai = MFMA(..., ai)` idiom forced ~20 preservation copies
// per step -> the measured 315 cy/step VALU-only regression vs R1's 27).
// Bias splats bgv[]/bdv hoisted out of the loop and only ever read as C operands.
// cs MFMAs issued first per kt-group; epilogue reordered cs->cn->(c write)->hn.
// Per-accumulator kt order unchanged -> identical arithmetic.
__global__ __launch_bounds__(512, 2) void tlstm_main(
    const __bf16* __restrict__ xb,   const float* __restrict__ ilg,
    const float* __restrict__ h0,    const float* __restrict__ c0,
    const float* __restrict__ Wih_f, const float* __restrict__ Whh_f,
    const float* __restrict__ bih_f, const float* __restrict__ bhh_f,
    const float* __restrict__ Wd_f,  const float* __restrict__ bd_f,
    const float* __restrict__ Wih_r, const float* __restrict__ Whh_r,
    const float* __restrict__ bih_r, const float* __restrict__ bhh_r,
    const float* __restrict__ Wd_r,  const float* __restrict__ bd_r,
    float* __restrict__ out)
{
    const int d    = blockIdx.x >> 4;
    const int b0   = (blockIdx.x & 15) * 4;
    const int tid  = threadIdx.x;
    const int w    = tid >> 6;
    const int lane = tid & 63;
    const int nl   = lane & 15;
    const int q    = lane >> 4;
    const int j    = w * 16 + nl;

    const float* Wih = d ? Wih_r : Wih_f;
    const float* Whh = d ? Whh_r : Whh_f;
    const float* bih = d ? bih_r : bih_f;
    const float* bhh = d ? bhh_r : bhh_f;
    const float* Wd  = d ? Wd_r  : Wd_f;
    const float* bd  = d ? bd_r  : bd_f;

    __shared__ __align__(16) __bf16 hc_a[2][16][LDSP];

    // resident weight B-frags: B[k][n] = W[n][k]; lane: n=nl(->j), k = kt*32 + q*8 ..+8
    bf16x8 whh_fr[4][4], wih_fr[4][4], wd_fr[4];
    #pragma unroll
    for (int g = 0; g < 4; ++g) {
        const int row = g * 128 + j;
        #pragma unroll
        for (int kt = 0; kt < 4; ++kt) {
            const int off = row * HID + kt * 32 + q * 8;
            wih_fr[g][kt] = cvt8(Wih + off);
            whh_fr[g][kt] = cvt8(Whh + off);
        }
    }
    #pragma unroll
    for (int kt = 0; kt < 4; ++kt)
        wd_fr[kt] = cvt8(Wd + j * HID + kt * 32 + q * 8);

    // loop-invariant bias splats, only ever read as MFMA C operands (never destroyed)
    f32x4 bgv[4];
    #pragma unroll
    for (int g = 0; g < 4; ++g) {
        const float b = bih[g * 128 + j] + bhh[g * 128 + j];
        bgv[g] = f32x4{b, b, b, b};
    }
    const float bias_d = bd[j];
    const f32x4 bdv = f32x4{bias_d, bias_d, bias_d, bias_d};

    // initial state for step 0 (dt=0): h at rows 4c+0, c at rows 4c+2
    for (int e = tid; e < 4 * HID; e += 512) {
        const int ci = e >> 7, k = e & 127;
        hc_a[0][ci * 4][k]     = (__bf16)h0[(d * BAT + b0 + ci) * HID + k];
        hc_a[0][ci * 4 + 2][k] = (__bf16)c0[(d * BAT + b0 + ci) * HID + k];
    }
    float c_st = c0[(d * BAT + b0 + q) * HID + j];
    __syncthreads();

    // running pointers
    const int t0      = d ? (SEQ - 1) : 0;
    const int tstep   = d ? -1 : 1;
    const int xstride = tstep * BAT * HID;
    const int istride = tstep * BAT;
    const int ostride = tstep * BAT * 256;

    // burst A-row = 4*chain + dt: chain = nl>>2, dt = nl&3
    const __bf16* xp0 = xb + (size_t)((t0 + tstep * (nl & 3)) * BAT + b0 + (nl >> 2)) * HID + q * 8;
    const float*  ip0 = ilg + (size_t)t0 * BAT + b0 + q;
    float*        op  = out + (size_t)(t0 * BAT + b0 + q) * 256 + d * 128 + j;

    // ---- pipeline state: chunk double-buffer, reload-own-buffer (distance 2 chunks)
    bf16x8 xfrA[4], xfrB[4];
    float  ilA[4], ilB[4];

    #pragma unroll
    for (int kt = 0; kt < 4; ++kt) {
        xfrA[kt] = *reinterpret_cast<const bf16x8*>(xp0 + kt * 32);                // chunk 0
        xfrB[kt] = *reinterpret_cast<const bf16x8*>(xp0 + 4 * xstride + kt * 32);  // chunk 1
    }
    #pragma unroll
    for (int dtv = 0; dtv < 4; ++dtv) {
        ilA[dtv] = ip0[dtv * istride];
        ilB[dtv] = ip0[(4 + dtv) * istride];
    }
    const __bf16* xpl = xp0 + 8 * xstride;   // loads target chunk n+2
    const float*  ipl = ip0 + 8 * istride;

    auto chunk = [&](bf16x8 (&xfrCur)[4], float (&ilCur)[4]) __attribute__((always_inline)) {
        // ---- burst: x-gate pre-acts for this chunk's 4 steps (reg r = step r) ----
        // First kt reads bgv[g] as C (D != C -> bgv preserved, no copies).
        f32x4 x0 = MFMA(xfrCur[0], wih_fr[0][0], bgv[0]);
        f32x4 x1 = MFMA(xfrCur[0], wih_fr[1][0], bgv[1]);
        f32x4 x2 = MFMA(xfrCur[0], wih_fr[2][0], bgv[2]);
        f32x4 x3 = MFMA(xfrCur[0], wih_fr[3][0], bgv[3]);
        #pragma unroll
        for (int kt = 1; kt < 4; ++kt) {
            x0 = MFMA(xfrCur[kt], wih_fr[0][kt], x0);
            x1 = MFMA(xfrCur[kt], wih_fr[1][kt], x1);
            x2 = MFMA(xfrCur[kt], wih_fr[2][kt], x2);
            x3 = MFMA(xfrCur[kt], wih_fr[3][kt], x3);
        }

        #pragma unroll
        for (int dt = 0; dt < 4; ++dt) {
            const int p  = dt & 1;
            const int pn = p ^ 1;
            const int hr = dt;              // gates' real C/D reg
            const int cr = (dt + 2) & 3;    // cs real C/D reg

            const float il_use = ilCur[dt];   // read before reload overwrites

            bf16x8 hcfr[4];
            #pragma unroll
            for (int kt = 0; kt < 4; ++kt)
                hcfr[kt] = *reinterpret_cast<const bf16x8*>(&hc_a[p][nl][kt * 32 + q * 8]);

            // Recurrent MFMAs. First kt consumes xacc/bdv as C operands (D != C ->
            // sources preserved, zero copy movs). cs chain issued first per kt-group
            // so the epilogue's serial tanh(cs) path starts earliest.
            f32x4 cA = MFMA(hcfr[0], wd_fr[0],     bdv);
            f32x4 g0 = MFMA(hcfr[0], whh_fr[0][0], x0);
            f32x4 g1 = MFMA(hcfr[0], whh_fr[1][0], x1);
            f32x4 g2 = MFMA(hcfr[0], whh_fr[2][0], x2);
            f32x4 g3 = MFMA(hcfr[0], whh_fr[3][0], x3);
            #pragma unroll
            for (int kt = 1; kt < 4; ++kt) {
                cA = MFMA(hcfr[kt], wd_fr[kt],      cA);
                g0 = MFMA(hcfr[kt], whh_fr[0][kt],  g0);
                g1 = MFMA(hcfr[kt], whh_fr[1][kt],  g1);
                g2 = MFMA(hcfr[kt], whh_fr[2][kt],  g2);
                g3 = MFMA(hcfr[kt], whh_fr[3][kt],  g3);
            }

            // prefetch chunk n+2: one x slice + one il per step into OWN buffers
            xfrCur[dt] = *reinterpret_cast<const bf16x8*>(xpl + dt * 32);
            ilCur[dt]  = ipl[dt * istride];

            // epilogue: serial cs path first; write cn to LDS as soon as known
            {
                const float cs   = tanh_f(cA[cr]);
                const float cadj = fmaf(cs, il_use, c_st);
                const float gf   = sig_f(g1[hr]);
                const float gi   = sig_f(g0[hr]);
                const float gg   = tanh_f(g2[hr]);
                const float cn   = gf * cadj + gi * gg;
                hc_a[pn][q * 4 + ((dt + 3) & 3)][j] = (__bf16)cn;   // c write early
                const float go   = sig_f(g3[hr]);
                const float hn   = go * tanh_f(cn);
                c_st = cn;
                hc_a[pn][q * 4 + ((dt + 1) & 3)][j] = (__bf16)hn;
                *op = hn;
            }
            op += ostride;

            // order LDS ops only; keep global loads/stores in flight across the barrier
            asm volatile("s_waitcnt lgkmcnt(0)\n\ts_barrier" ::: "memory");
        }
        xpl += 4 * xstride;
        ipl += 4 * istride;
    };

    for (int tc = 0; tc < SEQ / 4; tc += 2) {
        chunk(xfrA, ilA);
        chunk(xfrB, ilB);
    }
}

extern "C" void kernel_launch(void* const* d_in, const int* in_sizes, int n_in,
                              void* d_out, int out_size, void* d_ws, size_t ws_size,
                              hipStream_t stream) {
    const float* x     = (const float*)d_in[0];
    const float* h0    = (const float*)d_in[1];
    const float* c0    = (const float*)d_in[2];
    const float* dts   = (const float*)d_in[3];
    const float* Wih_f = (const float*)d_in[4];
    const float* Whh_f = (const float*)d_in[5];
    const float* bih_f = (const float*)d_in[6];
    const float* bhh_f = (const float*)d_in[7];
    const float* Wd_f  = (const float*)d_in[8];
    const float* bd_f  = (const float*)d_in[9];
    const float* Wih_r = (const float*)d_in[10];
    const float* Whh_r = (const float*)d_in[11];
    const float* bih_r = (const float*)d_in[12];
    const float* bhh_r = (const float*)d_in[13];
    const float* Wd_r  = (const float*)d_in[14];
    const float* bd_r  = (const float*)d_in[15];
    float* out = (float*)d_out;

    __bf16* xbuf = (__bf16*)((char*)d_ws + XB_OFF);
    float*  il   = (float*)((char*)d_ws + IL_OFF);

    cvt_x_kernel<<<16384, 256, 0, stream>>>(x, xbuf);
    prep_ilog_kernel<<<512, 256, 0, stream>>>(dts, il);

    tlstm_main<<<32, 512, 0, stream>>>(xbuf, il, h0, c0,
                                       Wih_f, Whh_f, bih_f, bhh_f, Wd_f, bd_f,
                                       Wih_r, Whh_r, bih_r, bhh_r, Wd_r, bd_r,
                                       out);
}